// Round 1
// baseline (2566.300 us; speedup 1.0000x reference)
//
#include <hip/hip_runtime.h>

#define HID 256
#define BT 64
#define DTC 0.05f

typedef unsigned int uint32;
typedef __attribute__((ext_vector_type(4))) float f32x4;
typedef __attribute__((ext_vector_type(8))) __bf16 bf16x8;

__device__ __forceinline__ unsigned short f2bf(float f) {
    unsigned int x = __float_as_uint(f);
    x += 0x7fffu + ((x >> 16) & 1u);
    return (unsigned short)(x >> 16);
}
__device__ __forceinline__ float bf2f(unsigned short s) {
    return __uint_as_float(((unsigned int)s) << 16);
}

// ---------------- prepack: fragment-linearized bf16 weight buffers ----------------
// ws layout (ushort elements):
#define OFF_FWDT 0         // [nt16][kk8][lane64][j8] : B[k][n]=kW2[n][k]  (fwd: a2 = h1 @ kW2^T)
#define OFF_BWDT 65536     // B[k][n]=kW2[k][n]                          (bwd: d1 = s2 @ kW2)
#define OFF_FWDV 131072
#define OFF_BWDV 196608
#define OFF_PROJT 262144   // [kk8][lane64][j8] : B[k][c]=kW1[k][c], c<3 else 0
#define OFF_PROJV 266240
#define TOTAL_PRE 270336

__global__ void prepack_kernel(const float* __restrict__ kW1, const float* __restrict__ kW2,
                               const float* __restrict__ pW1, const float* __restrict__ pW2,
                               unsigned short* __restrict__ ws) {
    int t = blockIdx.x * 256 + threadIdx.x;
    if (t >= TOTAL_PRE) return;
    float v;
    if (t < OFF_FWDV) {               // kW2 fwd/bwd
        int tt = t & 65535;
        bool bwd = t >= OFF_BWDT;
        int j = tt & 7, lane = (tt >> 3) & 63, kk = (tt >> 9) & 7, nt = tt >> 12;
        int n = nt * 16 + (lane & 15);
        int k = kk * 32 + (lane >> 4) * 8 + j;
        v = bwd ? kW2[k * HID + n] : kW2[n * HID + k];
    } else if (t < OFF_PROJT) {       // pW2 fwd/bwd
        int tt = (t - OFF_FWDV) & 65535;
        bool bwd = t >= OFF_BWDV;
        int j = tt & 7, lane = (tt >> 3) & 63, kk = (tt >> 9) & 7, nt = tt >> 12;
        int n = nt * 16 + (lane & 15);
        int k = kk * 32 + (lane >> 4) * 8 + j;
        v = bwd ? pW2[k * HID + n] : pW2[n * HID + k];
    } else if (t < OFF_PROJV) {       // kW1 projection (N=3 padded to 16)
        int tt = t - OFF_PROJT;
        int j = tt & 7, lane = (tt >> 3) & 63, kk = tt >> 9;
        int c = lane & 15;
        int k = kk * 32 + (lane >> 4) * 8 + j;
        v = (c < 3) ? kW1[k * 3 + c] : 0.f;
    } else {                          // pW1 projection (N=2 padded to 16)
        int tt = t - OFF_PROJV;
        int j = tt & 7, lane = (tt >> 3) & 63, kk = tt >> 9;
        int c = lane & 15;
        int k = kk * 32 + (lane >> 4) * 8 + j;
        v = (c < 2) ? pW1[k * 2 + c] : 0.f;
    }
    ws[t] = f2bf(v);
}

// ---------------- fused main kernel ----------------
// One workgroup = 64 samples, 4 waves. Wave w owns output columns [w*64, w*64+64).
// Activation LDS buffer [64][256] bf16, XOR-swizzled: byte_in_row ^= (row&7)<<4.
// MFMA 16x16x32 bf16. Assumed layouts:
//   A: lane holds A[m=lane&15][k=(lane>>4)*8 + j]
//   B: lane holds B[k=(lane>>4)*8 + j][n=lane&15]
//   C: lane reg r holds C[m=(lane>>4)*4 + r][n=lane&15]   (m89/m91-verified)

template <int IND, int NOUT>
__device__ __forceinline__ void run_net(
    char* bufc,
    const float* sh_sin, const float* sh_cos, const float* sh_pv,
    const float* W1, const float* b1v, const float* b2v, const float* W3,
    const unsigned short* fwdB, const unsigned short* bwdB, const unsigned short* projB,
    float* g0, float* g1, float* g2,
    int w, int lane)
{
    const int lr = lane & 15;
    const int lg = lane >> 4;

    // ---- phase 1: a1 = W1·x + b1 ; h1=softplus -> LDS ; sigmoid -> packed regs ----
    float w0[4], w1r[4], w2r[4], bb[4];
#pragma unroll
    for (int nt = 0; nt < 4; ++nt) {
        int j = w * 64 + nt * 16 + lr;
        w0[nt]  = W1[j * IND + 0];
        w1r[nt] = W1[j * IND + 1];
        w2r[nt] = (IND == 3) ? W1[j * IND + 2] : 0.f;
        bb[nt]  = b1v[j];
    }
    uint32 s1p[32];
#pragma unroll
    for (int mt = 0; mt < 4; ++mt) {
#pragma unroll
        for (int r = 0; r < 4; ++r) {
            int row = mt * 16 + lg * 4 + r;
            float sv = sh_sin[row], cv = sh_cos[row];
            float pv = (IND == 3) ? sh_pv[row] : 0.f;
            unsigned int rowx = (unsigned)(row & 7) << 4;
            char* rowp = bufc + row * 512;
            unsigned short lo = 0;
#pragma unroll
            for (int nt = 0; nt < 4; ++nt) {
                float x = fmaf(w0[nt], sv, bb[nt]);
                x = fmaf(w1r[nt], cv, x);
                if (IND == 3) x = fmaf(w2r[nt], pv, x);
                float e = __expf(-fabsf(x));
                float sp = fmaxf(x, 0.f) + __logf(1.f + e);
                float sg = __builtin_amdgcn_rcpf(1.f + e);
                sg = (x < 0.f) ? e * sg : sg;
                int j = w * 64 + nt * 16 + lr;
                *(unsigned short*)(rowp + ((j * 2) ^ rowx)) = f2bf(sp);
                unsigned short sgb = f2bf(sg);
                if ((nt & 1) == 0) lo = sgb;
                else s1p[(((mt * 4 + r) * 4) + nt) >> 1] = (uint32)lo | ((uint32)sgb << 16);
            }
        }
    }
    __syncthreads();   // h1 visible

    // ---- phase 2: fwd GEMM  acc = H1 @ W2^T ----
    f32x4 acc[4][4];
#pragma unroll
    for (int mt = 0; mt < 4; ++mt)
#pragma unroll
        for (int nt = 0; nt < 4; ++nt)
            acc[mt][nt] = (f32x4){0.f, 0.f, 0.f, 0.f};
#pragma unroll 1
    for (int kk = 0; kk < 8; ++kk) {
        bf16x8 af[4];
#pragma unroll
        for (int mt = 0; mt < 4; ++mt) {
            int row = mt * 16 + lr;
            int kb = kk * 64 + lg * 16;
            af[mt] = *(const bf16x8*)(bufc + row * 512 + (kb ^ ((row & 7) << 4)));
        }
        bf16x8 bfv[4];
#pragma unroll
        for (int nt = 0; nt < 4; ++nt) {
            int chunk = (w * 4 + nt) * 8 + kk;
            bfv[nt] = *(const bf16x8*)(fwdB + chunk * 512 + lane * 8);
        }
#pragma unroll
        for (int mt = 0; mt < 4; ++mt)
#pragma unroll
            for (int nt = 0; nt < 4; ++nt)
                acc[mt][nt] = __builtin_amdgcn_mfma_f32_16x16x32_bf16(af[mt], bfv[nt], acc[mt][nt], 0, 0, 0);
    }
    __syncthreads();   // everyone done reading h1

    // ---- phase 3: s2 = W3 ⊙ σ(a2 + b2) -> LDS ----
#pragma unroll
    for (int nt = 0; nt < 4; ++nt) {
        int i = w * 64 + nt * 16 + lr;
        float b2i = b2v[i];
        float w3i = W3[i];
#pragma unroll
        for (int mt = 0; mt < 4; ++mt) {
#pragma unroll
            for (int r = 0; r < 4; ++r) {
                float x = acc[mt][nt][r] + b2i;
                float e = __expf(-fabsf(x));
                float sg = __builtin_amdgcn_rcpf(1.f + e);
                sg = (x < 0.f) ? e * sg : sg;
                int row = mt * 16 + lg * 4 + r;
                *(unsigned short*)(bufc + row * 512 + ((i * 2) ^ ((row & 7) << 4))) = f2bf(w3i * sg);
            }
        }
    }
    __syncthreads();   // s2 visible

    // ---- phase 4: bwd GEMM  acc = S2 @ W2 ----
#pragma unroll
    for (int mt = 0; mt < 4; ++mt)
#pragma unroll
        for (int nt = 0; nt < 4; ++nt)
            acc[mt][nt] = (f32x4){0.f, 0.f, 0.f, 0.f};
#pragma unroll 1
    for (int kk = 0; kk < 8; ++kk) {
        bf16x8 af[4];
#pragma unroll
        for (int mt = 0; mt < 4; ++mt) {
            int row = mt * 16 + lr;
            int kb = kk * 64 + lg * 16;
            af[mt] = *(const bf16x8*)(bufc + row * 512 + (kb ^ ((row & 7) << 4)));
        }
        bf16x8 bfv[4];
#pragma unroll
        for (int nt = 0; nt < 4; ++nt) {
            int chunk = (w * 4 + nt) * 8 + kk;
            bfv[nt] = *(const bf16x8*)(bwdB + chunk * 512 + lane * 8);
        }
#pragma unroll
        for (int mt = 0; mt < 4; ++mt)
#pragma unroll
            for (int nt = 0; nt < 4; ++nt)
                acc[mt][nt] = __builtin_amdgcn_mfma_f32_16x16x32_bf16(af[mt], bfv[nt], acc[mt][nt], 0, 0, 0);
    }
    __syncthreads();   // everyone done reading s2

    // ---- phase 5: da1 = D1 ⊙ σ(a1) -> LDS ----
#pragma unroll
    for (int mt = 0; mt < 4; ++mt) {
#pragma unroll
        for (int r = 0; r < 4; ++r) {
            int row = mt * 16 + lg * 4 + r;
            unsigned int rowx = (unsigned)(row & 7) << 4;
            char* rowp = bufc + row * 512;
#pragma unroll
            for (int nt = 0; nt < 4; ++nt) {
                uint32 pr = s1p[(((mt * 4 + r) * 4) + nt) >> 1];
                float sg = bf2f((nt & 1) ? (unsigned short)(pr >> 16) : (unsigned short)(pr & 0xffffu));
                float v = acc[mt][nt][r] * sg;
                int j = w * 64 + nt * 16 + lr;
                *(unsigned short*)(rowp + ((j * 2) ^ rowx)) = f2bf(v);
            }
        }
    }
    __syncthreads();   // da1 visible

    // ---- phase 6: projection  g = dA1 @ W1  (N = NOUT, padded to 16) ----
    f32x4 pacc = (f32x4){0.f, 0.f, 0.f, 0.f};
#pragma unroll 1
    for (int kk = 0; kk < 8; ++kk) {
        int row = w * 16 + lr;
        int kb = kk * 64 + lg * 16;
        bf16x8 af = *(const bf16x8*)(bufc + row * 512 + (kb ^ ((row & 7) << 4)));
        bf16x8 bfv = *(const bf16x8*)(projB + kk * 512 + lane * 8);
        pacc = __builtin_amdgcn_mfma_f32_16x16x32_bf16(af, bfv, pacc, 0, 0, 0);
    }
    if (lr < NOUT) {
        float* dst = (lr == 0) ? g0 : ((lr == 1) ? g1 : g2);
#pragma unroll
        for (int r = 0; r < 4; ++r) dst[w * 16 + lg * 4 + r] = pacc[r];
    }
    __syncthreads();   // proj reads of buf done; gradients visible
}

__global__ __launch_bounds__(256, 3) void phgn_kernel(
    const float* __restrict__ q, const float* __restrict__ p, const float* __restrict__ u,
    const float* __restrict__ kW1, const float* __restrict__ kb1,
    const float* __restrict__ kb2, const float* __restrict__ kW3,
    const float* __restrict__ pW1, const float* __restrict__ pb1,
    const float* __restrict__ pb2, const float* __restrict__ pW3,
    const float* __restrict__ A, const float* __restrict__ Lp, const float* __restrict__ bctrl,
    const unsigned short* __restrict__ ws, float* __restrict__ out)
{
    __shared__ __attribute__((aligned(16))) unsigned short buf[BT * HID];
    __shared__ float shW1k[HID * 3], shb1k[HID], shb2k[HID], shW3k[HID];
    __shared__ float shW1p[HID * 2], shb1p[HID], shb2p[HID], shW3p[HID];
    __shared__ float sh_sin[BT], sh_cos[BT], sh_pv[BT];
    __shared__ float gx0[BT], gx1[BT], gx2[BT], ge0[BT], ge1[BT];

    const int tid = threadIdx.x;
    const int w = tid >> 6, lane = tid & 63;
    const int base = blockIdx.x * BT;

    for (int i = tid; i < HID * 3; i += 256) shW1k[i] = kW1[i];
    for (int i = tid; i < HID * 2; i += 256) shW1p[i] = pW1[i];
    {
        int i = tid;  // HID == blockDim
        shb1k[i] = kb1[i]; shb2k[i] = kb2[i]; shW3k[i] = kW3[i];
        shb1p[i] = pb1[i]; shb2p[i] = pb2[i]; shW3p[i] = pW3[i];
    }

    // M = (A - A^T) - L L^T,  L = tril(Lp,-1) + diag(softplus(diag(Lp)))
    float a01 = A[1], a10 = A[2];
    float l00 = log1pf(expf(Lp[0]));
    float l11 = log1pf(expf(Lp[3]));
    float l10 = Lp[2];
    float J01 = a01 - a10;
    float M00 = -(l00 * l00);
    float M01 = J01 - l00 * l10;
    float M10 = -J01 - l10 * l00;
    float M11 = -(l10 * l10 + l11 * l11);
    float bc = bctrl[0];

    float q0 = 0.f, p0 = 0.f, buv = 0.f, aq = 0.f, ap = 0.f;
    if (tid < BT) {
        q0 = q[base + tid]; p0 = p[base + tid]; buv = u[base + tid] * bc;
        float s, c; sincosf(q0, &s, &c);
        sh_sin[tid] = s; sh_cos[tid] = c; sh_pv[tid] = p0;
    }
    __syncthreads();

    char* bufc = (char*)buf;
#pragma unroll 1
    for (int s = 0; s < 4; ++s) {
        run_net<3, 3>(bufc, sh_sin, sh_cos, sh_pv, shW1k, shb1k, shb2k, shW3k,
                      ws + OFF_FWDT, ws + OFF_BWDT, ws + OFF_PROJT, gx0, gx1, gx2, w, lane);
        run_net<2, 2>(bufc, sh_sin, sh_cos, sh_pv, shW1p, shb1p, shb2p, shW3p,
                      ws + OFF_FWDV, ws + OFF_BWDV, ws + OFF_PROJV, ge0, ge1, ge1, w, lane);
        if (tid < BT) {
            float gq = (gx0[tid] + ge0[tid]) * sh_cos[tid] - (gx1[tid] + ge1[tid]) * sh_sin[tid];
            float gp = gx2[tid];
            float dq = M00 * gq + M01 * gp;
            float dp = M10 * gq + M11 * gp + buv;
            float wgt = (s == 0 || s == 3) ? 1.f : 2.f;
            aq += wgt * dq; ap += wgt * dp;
            if (s < 3) {
                float cs = (s == 2) ? 1.f : 0.5f;
                float qs = fmaf(cs * DTC, dq, q0);
                float ps = fmaf(cs * DTC, dp, p0);
                float sn, cn; sincosf(qs, &sn, &cn);
                sh_sin[tid] = sn; sh_cos[tid] = cn; sh_pv[tid] = ps;
            } else {
                float qn = fmaf(DTC / 6.f, aq, q0);
                float pn = fmaf(DTC / 6.f, ap, p0);
                ((float2*)out)[base + tid] = make_float2(qn, pn);
            }
        }
        __syncthreads();
    }
}

extern "C" void kernel_launch(void* const* d_in, const int* in_sizes, int n_in,
                              void* d_out, int out_size, void* d_ws, size_t ws_size,
                              hipStream_t stream) {
    const float* q    = (const float*)d_in[0];
    const float* p    = (const float*)d_in[1];
    const float* u    = (const float*)d_in[2];
    const float* kW1  = (const float*)d_in[3];
    const float* kb1  = (const float*)d_in[4];
    const float* kW2  = (const float*)d_in[5];
    const float* kb2  = (const float*)d_in[6];
    const float* kW3  = (const float*)d_in[7];
    const float* pW1  = (const float*)d_in[9];
    const float* pb1  = (const float*)d_in[10];
    const float* pW2  = (const float*)d_in[11];
    const float* pb2  = (const float*)d_in[12];
    const float* pW3  = (const float*)d_in[13];
    const float* A    = (const float*)d_in[15];
    const float* Lp   = (const float*)d_in[16];
    const float* bctl = (const float*)d_in[17];
    unsigned short* ws = (unsigned short*)d_ws;
    float* out = (float*)d_out;
    int B = in_sizes[0];

    prepack_kernel<<<(TOTAL_PRE + 255) / 256, 256, 0, stream>>>(kW1, kW2, pW1, pW2, ws);
    phgn_kernel<<<B / BT, 256, 0, stream>>>(q, p, u, kW1, kb1, kb2, kW3,
                                            pW1, pb1, pb2, pW3, A, Lp, bctl, ws, out);
}

// Round 2
// 1035.624 us; speedup vs baseline: 2.4780x; 2.4780x over previous
//
#include <hip/hip_runtime.h>

#define HID 256
#define BT 64
#define DTC 0.05f

typedef unsigned int uint32;
typedef __attribute__((ext_vector_type(4))) float f32x4;
typedef __attribute__((ext_vector_type(8))) __bf16 bf16x8;

__device__ __forceinline__ unsigned short f2bf(float f) {
    unsigned int x = __float_as_uint(f);
    x += 0x7fffu + ((x >> 16) & 1u);
    return (unsigned short)(x >> 16);
}
__device__ __forceinline__ float bf2f(unsigned short s) {
    return __uint_as_float(((unsigned int)s) << 16);
}

// ---------------- prepack: fragment-linearized bf16 weight buffers ----------------
// ws layout (ushort elements):
#define OFF_FWDT 0         // [nt16][kk8][lane64][j8] : B[k][n]=kW2[n][k]  (fwd: a2 = h1 @ kW2^T)
#define OFF_BWDT 65536     // B[k][n]=kW2[k][n]                          (bwd: d1 = s2 @ kW2)
#define OFF_FWDV 131072
#define OFF_BWDV 196608
#define OFF_PROJT 262144   // [kk8][lane64][j8] : B[k][c]=kW1[k][c], c<3 else 0
#define OFF_PROJV 266240
#define TOTAL_PRE 270336

__global__ void prepack_kernel(const float* __restrict__ kW1, const float* __restrict__ kW2,
                               const float* __restrict__ pW1, const float* __restrict__ pW2,
                               unsigned short* __restrict__ ws) {
    int t = blockIdx.x * 256 + threadIdx.x;
    if (t >= TOTAL_PRE) return;
    float v;
    if (t < OFF_FWDV) {               // kW2 fwd/bwd
        int tt = t & 65535;
        bool bwd = t >= OFF_BWDT;
        int j = tt & 7, lane = (tt >> 3) & 63, kk = (tt >> 9) & 7, nt = tt >> 12;
        int n = nt * 16 + (lane & 15);
        int k = kk * 32 + (lane >> 4) * 8 + j;
        v = bwd ? kW2[k * HID + n] : kW2[n * HID + k];
    } else if (t < OFF_PROJT) {       // pW2 fwd/bwd
        int tt = (t - OFF_FWDV) & 65535;
        bool bwd = t >= OFF_BWDV;
        int j = tt & 7, lane = (tt >> 3) & 63, kk = (tt >> 9) & 7, nt = tt >> 12;
        int n = nt * 16 + (lane & 15);
        int k = kk * 32 + (lane >> 4) * 8 + j;
        v = bwd ? pW2[k * HID + n] : pW2[n * HID + k];
    } else if (t < OFF_PROJV) {       // kW1 projection (N=3 padded to 16)
        int tt = t - OFF_PROJT;
        int j = tt & 7, lane = (tt >> 3) & 63, kk = tt >> 9;
        int c = lane & 15;
        int k = kk * 32 + (lane >> 4) * 8 + j;
        v = (c < 3) ? kW1[k * 3 + c] : 0.f;
    } else {                          // pW1 projection (N=2 padded to 16)
        int tt = t - OFF_PROJV;
        int j = tt & 7, lane = (tt >> 3) & 63, kk = tt >> 9;
        int c = lane & 15;
        int k = kk * 32 + (lane >> 4) * 8 + j;
        v = (c < 2) ? pW1[k * 2 + c] : 0.f;
    }
    ws[t] = f2bf(v);
}

// ---------------- fused main kernel ----------------
// 512 threads = 8 waves per block, 64 samples per block.
// Wave w owns output columns [w*32, w*32+32) -> acc[4][2] (32 VGPRs).
// bufA holds h1 (then da1 in place); bufB holds s2. sigma(a1) is NOT kept in
// registers: recovered as 1 - exp(-h1) from LDS (exact identity), which is
// what lets register pressure fit the __launch_bounds__(512,4) cap of 128.
// LDS rows XOR-swizzled: byte_in_row ^= (row&7)<<4.
// MFMA 16x16x32 bf16 layouts (verified round 1, absmax 1.6e-2):
//   A: lane holds A[m=lane&15][k=(lane>>4)*8 + j]
//   B: lane holds B[k=(lane>>4)*8 + j][n=lane&15]
//   C: lane reg r holds C[m=(lane>>4)*4 + r][n=lane&15]

struct NetRegs { float w0[2], w1[2], w2[2], b1[2], b2[2], w3[2]; };

template <int IND, int NOUT>
__device__ __forceinline__ void run_net(
    char* bufAc, char* bufBc,
    const float* sh_sin, const float* sh_cos, const float* sh_pv,
    const NetRegs& R,
    const unsigned short* __restrict__ fwdB, const unsigned short* __restrict__ bwdB,
    const unsigned short* __restrict__ projB,
    float* g0, float* g1, float* g2,
    int w, int lane)
{
    const int lr = lane & 15;
    const int lg = lane >> 4;

    // ---- phase 1: a1 = W1·x + b1 ; h1 = softplus -> bufA ----
#pragma unroll
    for (int mt = 0; mt < 4; ++mt) {
#pragma unroll
        for (int r = 0; r < 4; ++r) {
            int row = mt * 16 + lg * 4 + r;
            float sv = sh_sin[row], cv = sh_cos[row];
            float pv = (IND == 3) ? sh_pv[row] : 0.f;
            unsigned int rowx = (unsigned)(row & 7) << 4;
            char* rowp = bufAc + row * 512;
#pragma unroll
            for (int nt = 0; nt < 2; ++nt) {
                float x = fmaf(R.w0[nt], sv, R.b1[nt]);
                x = fmaf(R.w1[nt], cv, x);
                if (IND == 3) x = fmaf(R.w2[nt], pv, x);
                float e = __expf(-fabsf(x));
                float sp = fmaxf(x, 0.f) + __logf(1.f + e);
                int j = w * 32 + nt * 16 + lr;
                *(unsigned short*)(rowp + ((j * 2) ^ rowx)) = f2bf(sp);
            }
        }
    }
    __syncthreads();   // h1 visible

    // ---- phase 2: fwd GEMM  acc = H1 @ W2^T  (reads bufA) ----
    const unsigned int arx = (unsigned)(lr & 7) << 4;
    f32x4 acc[4][2];
#pragma unroll
    for (int mt = 0; mt < 4; ++mt)
#pragma unroll
        for (int nt = 0; nt < 2; ++nt)
            acc[mt][nt] = (f32x4){0.f, 0.f, 0.f, 0.f};
#pragma unroll 1
    for (int kk = 0; kk < 8; ++kk) {
        int kb = kk * 64 + lg * 16;
        bf16x8 af[4];
#pragma unroll
        for (int mt = 0; mt < 4; ++mt)
            af[mt] = *(const bf16x8*)(bufAc + (mt * 16 + lr) * 512 + (kb ^ arx));
        bf16x8 bv[2];
#pragma unroll
        for (int nt = 0; nt < 2; ++nt)
            bv[nt] = *(const bf16x8*)(fwdB + ((w * 2 + nt) * 8 + kk) * 512 + lane * 8);
#pragma unroll
        for (int mt = 0; mt < 4; ++mt)
#pragma unroll
            for (int nt = 0; nt < 2; ++nt)
                acc[mt][nt] = __builtin_amdgcn_mfma_f32_16x16x32_bf16(af[mt], bv[nt], acc[mt][nt], 0, 0, 0);
    }

    // ---- phase 3: s2 = W3 ⊙ σ(a2 + b2) -> bufB (no barrier needed before) ----
#pragma unroll
    for (int nt = 0; nt < 2; ++nt) {
        int i = w * 32 + nt * 16 + lr;
        float b2i = R.b2[nt];
        float w3i = R.w3[nt];
#pragma unroll
        for (int mt = 0; mt < 4; ++mt) {
#pragma unroll
            for (int r = 0; r < 4; ++r) {
                float x = acc[mt][nt][r] + b2i;
                float e = __expf(-fabsf(x));
                float sg = __builtin_amdgcn_rcpf(1.f + e);
                sg = (x < 0.f) ? e * sg : sg;
                int row = mt * 16 + lg * 4 + r;
                *(unsigned short*)(bufBc + row * 512 + ((i * 2) ^ ((unsigned)(row & 7) << 4))) = f2bf(w3i * sg);
            }
        }
    }
    __syncthreads();   // s2 visible

    // ---- phase 4: bwd GEMM  acc = S2 @ W2  (reads bufB) ----
#pragma unroll
    for (int mt = 0; mt < 4; ++mt)
#pragma unroll
        for (int nt = 0; nt < 2; ++nt)
            acc[mt][nt] = (f32x4){0.f, 0.f, 0.f, 0.f};
#pragma unroll 1
    for (int kk = 0; kk < 8; ++kk) {
        int kb = kk * 64 + lg * 16;
        bf16x8 af[4];
#pragma unroll
        for (int mt = 0; mt < 4; ++mt)
            af[mt] = *(const bf16x8*)(bufBc + (mt * 16 + lr) * 512 + (kb ^ arx));
        bf16x8 bv[2];
#pragma unroll
        for (int nt = 0; nt < 2; ++nt)
            bv[nt] = *(const bf16x8*)(bwdB + ((w * 2 + nt) * 8 + kk) * 512 + lane * 8);
#pragma unroll
        for (int mt = 0; mt < 4; ++mt)
#pragma unroll
            for (int nt = 0; nt < 2; ++nt)
                acc[mt][nt] = __builtin_amdgcn_mfma_f32_16x16x32_bf16(af[mt], bv[nt], acc[mt][nt], 0, 0, 0);
    }

    // ---- phase 5: da1 = D1 ⊙ σ(a1) in place in bufA; σ(a1) = 1 - exp(-h1) ----
#pragma unroll
    for (int mt = 0; mt < 4; ++mt) {
#pragma unroll
        for (int r = 0; r < 4; ++r) {
            int row = mt * 16 + lg * 4 + r;
            unsigned int rowx = (unsigned)(row & 7) << 4;
            char* rowp = bufAc + row * 512;
#pragma unroll
            for (int nt = 0; nt < 2; ++nt) {
                int j = w * 32 + nt * 16 + lr;
                unsigned short* ap = (unsigned short*)(rowp + ((j * 2) ^ rowx));
                float h1 = bf2f(*ap);
                float sg = 1.f - __expf(-h1);
                *ap = f2bf(acc[mt][nt][r] * sg);
            }
        }
    }
    __syncthreads();   // da1 visible

    // ---- phase 6: projection  g = dA1 @ W1  (waves 0-3 only; N padded to 16) ----
    if (w < 4) {
        f32x4 pacc = (f32x4){0.f, 0.f, 0.f, 0.f};
#pragma unroll 1
        for (int kk = 0; kk < 8; ++kk) {
            int kb = kk * 64 + lg * 16;
            bf16x8 af = *(const bf16x8*)(bufAc + (w * 16 + lr) * 512 + (kb ^ arx));
            bf16x8 bv = *(const bf16x8*)(projB + kk * 512 + lane * 8);
            pacc = __builtin_amdgcn_mfma_f32_16x16x32_bf16(af, bv, pacc, 0, 0, 0);
        }
        if (lr < NOUT) {
            float* dst = (lr == 0) ? g0 : ((lr == 1) ? g1 : g2);
#pragma unroll
            for (int r = 0; r < 4; ++r) dst[w * 16 + lg * 4 + r] = pacc[r];
        }
    }
    __syncthreads();   // proj reads of bufA done; gradients visible
}

__global__ __launch_bounds__(512, 4) void phgn_kernel(
    const float* __restrict__ q, const float* __restrict__ p, const float* __restrict__ u,
    const float* __restrict__ kW1, const float* __restrict__ kb1,
    const float* __restrict__ kb2, const float* __restrict__ kW3,
    const float* __restrict__ pW1, const float* __restrict__ pb1,
    const float* __restrict__ pb2, const float* __restrict__ pW3,
    const float* __restrict__ A, const float* __restrict__ Lp, const float* __restrict__ bctrl,
    const unsigned short* __restrict__ ws, float* __restrict__ out)
{
    __shared__ __attribute__((aligned(16))) unsigned short bufA[BT * HID];
    __shared__ __attribute__((aligned(16))) unsigned short bufB[BT * HID];
    __shared__ float sh_sin[BT], sh_cos[BT], sh_pv[BT];
    __shared__ float gx0[BT], gx1[BT], gx2[BT], ge0[BT], ge1[BT];

    const int tid = threadIdx.x;
    const int w = tid >> 6, lane = tid & 63;
    const int lr = lane & 15;
    const int base = blockIdx.x * BT;

    // Hoist per-thread weights (stage-invariant) into registers, once.
    NetRegs RT, RV;
#pragma unroll
    for (int nt = 0; nt < 2; ++nt) {
        int j = w * 32 + nt * 16 + lr;
        RT.w0[nt] = kW1[j * 3 + 0];
        RT.w1[nt] = kW1[j * 3 + 1];
        RT.w2[nt] = kW1[j * 3 + 2];
        RT.b1[nt] = kb1[j];
        RT.b2[nt] = kb2[j];
        RT.w3[nt] = kW3[j];
        RV.w0[nt] = pW1[j * 2 + 0];
        RV.w1[nt] = pW1[j * 2 + 1];
        RV.w2[nt] = 0.f;
        RV.b1[nt] = pb1[j];
        RV.b2[nt] = pb2[j];
        RV.w3[nt] = pW3[j];
    }

    // M = (A - A^T) - L L^T,  L = tril(Lp,-1) + diag(softplus(diag(Lp)))
    float a01 = A[1], a10 = A[2];
    float l00 = log1pf(expf(Lp[0]));
    float l11 = log1pf(expf(Lp[3]));
    float l10 = Lp[2];
    float J01 = a01 - a10;
    float M00 = -(l00 * l00);
    float M01 = J01 - l00 * l10;
    float M10 = -J01 - l10 * l00;
    float M11 = -(l10 * l10 + l11 * l11);
    float bc = bctrl[0];

    float q0 = 0.f, p0 = 0.f, buv = 0.f, aq = 0.f, ap = 0.f;
    if (tid < BT) {
        q0 = q[base + tid]; p0 = p[base + tid]; buv = u[base + tid] * bc;
        float s, c; sincosf(q0, &s, &c);
        sh_sin[tid] = s; sh_cos[tid] = c; sh_pv[tid] = p0;
    }
    __syncthreads();

    char* bufAc = (char*)bufA;
    char* bufBc = (char*)bufB;
#pragma unroll 1
    for (int s = 0; s < 4; ++s) {
        run_net<3, 3>(bufAc, bufBc, sh_sin, sh_cos, sh_pv, RT,
                      ws + OFF_FWDT, ws + OFF_BWDT, ws + OFF_PROJT, gx0, gx1, gx2, w, lane);
        run_net<2, 2>(bufAc, bufBc, sh_sin, sh_cos, sh_pv, RV,
                      ws + OFF_FWDV, ws + OFF_BWDV, ws + OFF_PROJV, ge0, ge1, ge1, w, lane);
        if (tid < BT) {
            float gq = (gx0[tid] + ge0[tid]) * sh_cos[tid] - (gx1[tid] + ge1[tid]) * sh_sin[tid];
            float gp = gx2[tid];
            float dq = M00 * gq + M01 * gp;
            float dp = M10 * gq + M11 * gp + buv;
            float wgt = (s == 0 || s == 3) ? 1.f : 2.f;
            aq += wgt * dq; ap += wgt * dp;
            if (s < 3) {
                float cs = (s == 2) ? 1.f : 0.5f;
                float qs = fmaf(cs * DTC, dq, q0);
                float ps = fmaf(cs * DTC, dp, p0);
                float sn, cn; sincosf(qs, &sn, &cn);
                sh_sin[tid] = sn; sh_cos[tid] = cn; sh_pv[tid] = ps;
            } else {
                float qn = fmaf(DTC / 6.f, aq, q0);
                float pn = fmaf(DTC / 6.f, ap, p0);
                ((float2*)out)[base + tid] = make_float2(qn, pn);
            }
        }
        __syncthreads();
    }
}

extern "C" void kernel_launch(void* const* d_in, const int* in_sizes, int n_in,
                              void* d_out, int out_size, void* d_ws, size_t ws_size,
                              hipStream_t stream) {
    const float* q    = (const float*)d_in[0];
    const float* p    = (const float*)d_in[1];
    const float* u    = (const float*)d_in[2];
    const float* kW1  = (const float*)d_in[3];
    const float* kb1  = (const float*)d_in[4];
    const float* kW2  = (const float*)d_in[5];
    const float* kb2  = (const float*)d_in[6];
    const float* kW3  = (const float*)d_in[7];
    const float* pW1  = (const float*)d_in[9];
    const float* pb1  = (const float*)d_in[10];
    const float* pW2  = (const float*)d_in[11];
    const float* pb2  = (const float*)d_in[12];
    const float* pW3  = (const float*)d_in[13];
    const float* A    = (const float*)d_in[15];
    const float* Lp   = (const float*)d_in[16];
    const float* bctl = (const float*)d_in[17];
    unsigned short* ws = (unsigned short*)d_ws;
    float* out = (float*)d_out;
    int B = in_sizes[0];

    prepack_kernel<<<(TOTAL_PRE + 255) / 256, 256, 0, stream>>>(kW1, kW2, pW1, pW2, ws);
    phgn_kernel<<<B / BT, 512, 0, stream>>>(q, p, u, kW1, kb1, kb2, kW3,
                                            pW1, pb1, pb2, pW3, A, Lp, bctl, ws, out);
}